// Round 1
// baseline (136.113 us; speedup 1.0000x reference)
//
#include <hip/hip_runtime.h>
#include <hip/hip_bf16.h>

// Problem: nll(pred, target) + symmetric chamfer(reg[B,N,3], point1[B,M,3])
// B=16, N=M=2048, NUM_CLASSES=40. Output: 1 fp32 scalar.
//
// Design:
//  - kernel nll_init: 1 thread computes -mean(pred[b,target[b]]) and writes d_out[0].
//  - kernel chamfer_dir: grid = 2 dirs * 16 batches * 8 n-chunks = 256 blocks,
//    512 threads (256 query pts x 2 m-halves). Full target point set (2048 pts)
//    staged in LDS padded to float4 (32KB) -> inner loop is ds_read_b128
//    broadcast + 7 VALU. Two m-halves combined via LDS, block-reduce sum,
//    one atomicAdd per block into d_out (device-scope, safe cross-XCD).

#define BQ 256        // query points per block
#define THREADS 512   // BQ * 2 m-halves
#define NPTS 2048     // N == M
#define BATCH 16
#define NCLS 40

__global__ __launch_bounds__(64) void nll_init_kernel(const float* __restrict__ pred,
                                                      const int* __restrict__ target,
                                                      float* __restrict__ out) {
    if (threadIdx.x == 0 && blockIdx.x == 0) {
        float s = 0.f;
        for (int b = 0; b < BATCH; ++b) {
            s += pred[b * NCLS + target[b]];
        }
        out[0] = -s * (1.0f / BATCH);
    }
}

__global__ __launch_bounds__(THREADS) void chamfer_kernel(const float* __restrict__ reg,
                                                          const float* __restrict__ pt,
                                                          float* __restrict__ out) {
    // decode block: dir (0: query=reg,target=pt; 1: query=pt,target=reg), b, chunk
    int bid = blockIdx.x;
    int dir = bid >> 7;          // 128 blocks per direction
    int rem = bid & 127;
    int b = rem >> 3;            // 16 batches
    int chunk = rem & 7;         // 8 chunks of 256 query points

    const float* __restrict__ X = dir ? pt : reg;   // queries  [B, 2048, 3]
    const float* __restrict__ Y = dir ? reg : pt;   // targets  [B, 2048, 3]

    __shared__ float4 sy[NPTS];      // padded target points, 32KB
    __shared__ float comb[BQ];
    __shared__ float wsum[THREADS / 64];

    int tid = threadIdx.x;
    int half = tid >> 8;             // which m-half this thread scans
    int qi = tid & (BQ - 1);         // query slot within chunk

    // stage all 2048 target points of batch b into LDS (pad stride 3 -> 4)
    float* syf = (float*)sy;
    const float* Yb = Y + (size_t)b * (NPTS * 3);
    for (int i = tid; i < NPTS * 3; i += THREADS) {
        int p = i / 3;
        int c = i - p * 3;
        syf[p * 4 + c] = Yb[i];
    }
    __syncthreads();

    // my query point
    int n = chunk * BQ + qi;
    const float* xp = X + (size_t)b * (NPTS * 3) + n * 3;
    float x0 = xp[0], x1 = xp[1], x2 = xp[2];

    // min over this thread's m-half
    float mind = 3.0e38f;
    int mbase = half << 10;          // 0 or 1024
#pragma unroll 8
    for (int m = 0; m < NPTS / 2; ++m) {
        float4 y = sy[mbase + m];
        float dx = x0 - y.x;
        float dy = x1 - y.y;
        float dz = x2 - y.z;
        float d = fmaf(dx, dx, fmaf(dy, dy, dz * dz));
        mind = fminf(mind, d);
    }

    // combine the two halves per query point
    if (half == 0) comb[qi] = mind;
    __syncthreads();
    float v = 0.f;
    if (half == 1) v = fminf(comb[qi], mind);   // threads 256..511 hold final mins

    // block reduction (sum of 256 final mins; half-0 threads contribute 0)
    for (int off = 32; off > 0; off >>= 1) v += __shfl_down(v, off);
    int lane = tid & 63, wid = tid >> 6;
    if (lane == 0) wsum[wid] = v;
    __syncthreads();
    if (tid == 0) {
        float s = 0.f;
#pragma unroll
        for (int w = 0; w < THREADS / 64; ++w) s += wsum[w];
        // scale: reg_loss = sum(dist1)/(B*N) + sum(dist2)/(B*M); N==M==2048
        atomicAdd(out, s * (1.0f / (BATCH * NPTS)));
    }
}

extern "C" void kernel_launch(void* const* d_in, const int* in_sizes, int n_in,
                              void* d_out, int out_size, void* d_ws, size_t ws_size,
                              hipStream_t stream) {
    const float* reg    = (const float*)d_in[0];   // [16,2048,3] fp32
    const float* point1 = (const float*)d_in[1];   // [16,2048,3] fp32
    const float* pred   = (const float*)d_in[2];   // [16,40] fp32 log-probs
    const int*   target = (const int*)d_in[3];     // [16] int
    float* out = (float*)d_out;

    // 1) write nll into d_out (also initializes the poisoned output)
    nll_init_kernel<<<1, 64, 0, stream>>>(pred, target, out);
    // 2) chamfer both directions, accumulate into d_out
    chamfer_kernel<<<256, THREADS, 0, stream>>>(reg, point1, out);
}

// Round 2
// 78.139 us; speedup vs baseline: 1.7419x; 1.7419x over previous
//
#include <hip/hip_runtime.h>
#include <hip/hip_bf16.h>

// nll(pred,target) + symmetric chamfer(reg[16,2048,3], point1[16,2048,3]) -> scalar.
//
// chamfer_kernel: 512 blocks x 512 threads.
//   block = (dir, batch, chunk-of-128-queries). Thread = (qgroup g in 0..15, segment s in 0..31).
//   Each thread: 8 queries (register-tiled) x 64 targets (segment s).
//   LDS: targets as float4 (y0,y1,y2,|y|^2)  [32KB], queries as float4 (-2x0,-2x1,-2x2,|x|^2) [2KB],
//        per-(query,segment) min table [128][33] fp32 [16.9KB].
//   Per pair: d' = fma(-2x0,y0, fma(-2x1,y1, fma(-2x2,y2, |y|^2))) ; min-chain.
//   dist = |x|^2 + min d'  (matches reference's x^2+y^2-2xy formulation).
//   Block: min over 32 segments per query, sum 128 queries, one atomicAdd.

#define NPTS 2048
#define BATCH 16
#define NCLS 40
#define QB   128   // queries per block
#define KQ   8     // queries per thread
#define NSEG 32    // target segments
#define SEGLEN (NPTS / NSEG)   // 64
#define THREADS (QB / KQ * NSEG)  // 512

__global__ __launch_bounds__(64) void nll_init_kernel(const float* __restrict__ pred,
                                                      const int* __restrict__ target,
                                                      float* __restrict__ out) {
    int lane = threadIdx.x;
    float v = 0.f;
    if (lane < BATCH) v = pred[lane * NCLS + target[lane]];
    for (int off = 32; off > 0; off >>= 1) v += __shfl_down(v, off);
    if (lane == 0) out[0] = -v * (1.0f / BATCH);
}

__global__ __launch_bounds__(THREADS, 4) void chamfer_kernel(const float* __restrict__ reg,
                                                             const float* __restrict__ pt,
                                                             float* __restrict__ out) {
    int bid = blockIdx.x;
    int dir = bid >> 8;           // 256 blocks per direction
    int rem = bid & 255;
    int b = rem >> 4;             // 16 batches
    int chunk = rem & 15;         // 16 chunks of 128 queries
    int qbase = chunk * QB;

    const float* __restrict__ X = dir ? pt : reg;   // queries  [B,2048,3]
    const float* __restrict__ Y = dir ? reg : pt;   // targets  [B,2048,3]

    __shared__ float4 sy[NPTS];          // 32 KB: targets + |y|^2
    __shared__ float4 sq[QB];            // 2 KB: -2x + |x|^2
    __shared__ float  sm[QB * (NSEG + 1)]; // 16.9 KB min table, stride 33
    __shared__ float  wsum[THREADS / 64];

    int tid = threadIdx.x;
    int g = tid & 15;             // query group
    int s = tid >> 4;             // target segment

    // stage targets (compute |y|^2 on the fly)
    const float* Yb = Y + (size_t)b * (NPTS * 3);
    for (int p = tid; p < NPTS; p += THREADS) {
        float y0 = Yb[p * 3], y1 = Yb[p * 3 + 1], y2 = Yb[p * 3 + 2];
        sy[p] = make_float4(y0, y1, y2, fmaf(y0, y0, fmaf(y1, y1, y2 * y2)));
    }
    // stage queries
    const float* Xb = X + (size_t)b * (NPTS * 3) + (size_t)qbase * 3;
    if (tid < QB) {
        float x0 = Xb[tid * 3], x1 = Xb[tid * 3 + 1], x2 = Xb[tid * 3 + 2];
        sq[tid] = make_float4(-2.f * x0, -2.f * x1, -2.f * x2,
                              fmaf(x0, x0, fmaf(x1, x1, x2 * x2)));
    }
    __syncthreads();

    // register-tile 8 queries
    float ax[KQ], ay[KQ], az[KQ], x2[KQ], mn[KQ];
#pragma unroll
    for (int i = 0; i < KQ; ++i) {
        float4 q = sq[g * KQ + i];
        ax[i] = q.x; ay[i] = q.y; az[i] = q.z; x2[i] = q.w;
        mn[i] = 3.0e38f;
    }

    const float4* ys = sy + s * SEGLEN;
#pragma unroll 4
    for (int m = 0; m < SEGLEN; ++m) {
        float4 y = ys[m];
#pragma unroll
        for (int i = 0; i < KQ; ++i) {
            float d = fmaf(ax[i], y.x, fmaf(ay[i], y.y, fmaf(az[i], y.z, y.w)));
            mn[i] = fminf(mn[i], d);
        }
    }

    // write per-(query, segment) results
#pragma unroll
    for (int i = 0; i < KQ; ++i) {
        sm[(g * KQ + i) * (NSEG + 1) + s] = x2[i] + mn[i];
    }
    __syncthreads();

    // min over segments, then block-wide sum
    float v = 0.f;
    if (tid < QB) {
        float mv = 3.0e38f;
#pragma unroll 8
        for (int s2 = 0; s2 < NSEG; ++s2) mv = fminf(mv, sm[tid * (NSEG + 1) + s2]);
        v = mv;
    }
    for (int off = 32; off > 0; off >>= 1) v += __shfl_down(v, off);
    int lane = tid & 63, wid = tid >> 6;
    if (lane == 0) wsum[wid] = v;
    __syncthreads();
    if (tid == 0) {
        float ssum = 0.f;
#pragma unroll
        for (int w = 0; w < THREADS / 64; ++w) ssum += wsum[w];
        atomicAdd(out, ssum * (1.0f / (BATCH * NPTS)));
    }
}

extern "C" void kernel_launch(void* const* d_in, const int* in_sizes, int n_in,
                              void* d_out, int out_size, void* d_ws, size_t ws_size,
                              hipStream_t stream) {
    const float* reg    = (const float*)d_in[0];
    const float* point1 = (const float*)d_in[1];
    const float* pred   = (const float*)d_in[2];
    const int*   target = (const int*)d_in[3];
    float* out = (float*)d_out;

    nll_init_kernel<<<1, 64, 0, stream>>>(pred, target, out);
    chamfer_kernel<<<512, THREADS, 0, stream>>>(reg, point1, out);
}